// Round 1
// baseline (52.022 us; speedup 1.0000x reference)
//
#include <hip/hip_runtime.h>
#include <math.h>

// Problem constants (B,C,H,W)=(16,1,1024,1024), patch=128
constexpr int B_ = 16;
constexpr int HW = 1024;
constexpr int P  = 128;
constexpr int NPATCH = 1024;       // 16 samples * 8 * 8
constexpr int THREADS1 = 512;

// Kernel 1: one block per 128x128 patch.
// Produces per-patch record: {bce_partial_sum, min(pred), max(pred), valid}
__global__ __launch_bounds__(THREADS1)
void patch_stats_kernel(const float* __restrict__ labels,
                        const float* __restrict__ preds,
                        float4* __restrict__ ws)
{
    const int pid = blockIdx.x;
    const int s  = pid >> 6;          // sample
    const int ph = (pid >> 3) & 7;    // patch row
    const int pw = pid & 7;           // patch col
    const size_t base = (size_t)s * (HW * HW) + (size_t)ph * P * HW + (size_t)pw * P;

    const int tid  = threadIdx.x;
    const int col4 = (tid & 31) << 2; // float offset within a 128-float row (32 float4/row)
    const int row0 = tid >> 5;        // 0..15; 512 threads cover 16 rows per pass

    float bce  = 0.0f;
    float xmin =  3.0e38f, xmax = -3.0e38f;
    float tmin =  3.0e38f, tmax = -3.0e38f;

    #pragma unroll
    for (int r = row0; r < P; r += 16) {
        const size_t off = base + (size_t)r * HW + col4;
        const float4 x4 = *reinterpret_cast<const float4*>(preds  + off);
        const float4 t4 = *reinterpret_cast<const float4*>(labels + off);
        const float xs[4] = {x4.x, x4.y, x4.z, x4.w};
        const float ts[4] = {t4.x, t4.y, t4.z, t4.w};
        #pragma unroll
        for (int j = 0; j < 4; ++j) {
            const float x = xs[j], t = ts[j];
            bce += fmaxf(x, 0.0f) - x * t + log1pf(__expf(-fabsf(x)));
            xmin = fminf(xmin, x); xmax = fmaxf(xmax, x);
            tmin = fminf(tmin, t); tmax = fmaxf(tmax, t);
        }
    }

    // wave(64) butterfly-down reduction
    #pragma unroll
    for (int o = 32; o > 0; o >>= 1) {
        bce += __shfl_down(bce, o);
        xmin = fminf(xmin, __shfl_down(xmin, o));
        xmax = fmaxf(xmax, __shfl_down(xmax, o));
        tmin = fminf(tmin, __shfl_down(tmin, o));
        tmax = fmaxf(tmax, __shfl_down(tmax, o));
    }

    __shared__ float s_bce[8], s_xmin[8], s_xmax[8], s_tmin[8], s_tmax[8];
    const int wave = tid >> 6;
    const int lane = tid & 63;
    if (lane == 0) {
        s_bce[wave] = bce;  s_xmin[wave] = xmin; s_xmax[wave] = xmax;
        s_tmin[wave] = tmin; s_tmax[wave] = tmax;
    }
    __syncthreads();
    if (tid == 0) {
        float b = 0.0f, xi = 3.0e38f, xa = -3.0e38f, ti = 3.0e38f, ta = -3.0e38f;
        #pragma unroll
        for (int w = 0; w < THREADS1 / 64; ++w) {
            b += s_bce[w];
            xi = fminf(xi, s_xmin[w]); xa = fmaxf(xa, s_xmax[w]);
            ti = fminf(ti, s_tmin[w]); ta = fmaxf(ta, s_tmax[w]);
        }
        // gt = 1 - t; valid = (max gt > 0.5) && (min gt < 0.5) == (min t < 0.5) && (max t > 0.5)
        const float valid = (ti < 0.5f && ta > 0.5f) ? 1.0f : 0.0f;
        ws[pid] = make_float4(b, xi, xa, valid);
    }
}

// Kernel 2: reduce 1024 patch records to the scalar loss. Overwrites out[0].
__global__ __launch_bounds__(256)
void final_reduce_kernel(const float4* __restrict__ ws, float* __restrict__ out)
{
    const int tid = threadIdx.x;
    float bce = 0.0f, topo = 0.0f;
    for (int i = tid; i < NPATCH; i += 256) {
        const float4 rec = ws[i];
        bce += rec.x;
        if (rec.w > 0.5f) {
            // lh = sigmoid(1 - x) is decreasing in x:
            // pmax = sigmoid(1 - xmin), pmin = sigmoid(1 - xmax)
            const float pmax = 1.0f / (1.0f + __expf(rec.y - 1.0f));
            const float pmin = 1.0f / (1.0f + __expf(rec.z - 1.0f));
            topo += (pmax - 1.0f) * (pmax - 1.0f) + pmin * pmin;
        }
    }
    #pragma unroll
    for (int o = 32; o > 0; o >>= 1) {
        bce  += __shfl_down(bce, o);
        topo += __shfl_down(topo, o);
    }
    __shared__ float s_b[4], s_t[4];
    const int wave = tid >> 6;
    const int lane = tid & 63;
    if (lane == 0) { s_b[wave] = bce; s_t[wave] = topo; }
    __syncthreads();
    if (tid == 0) {
        const float bt = s_b[0] + s_b[1] + s_b[2] + s_b[3];
        const float tt = s_t[0] + s_t[1] + s_t[2] + s_t[3];
        out[0] = bt / (float)((size_t)B_ * HW * HW) + tt / (float)B_;
    }
}

extern "C" void kernel_launch(void* const* d_in, const int* in_sizes, int n_in,
                              void* d_out, int out_size, void* d_ws, size_t ws_size,
                              hipStream_t stream) {
    const float* labels = (const float*)d_in[0];
    const float* preds  = (const float*)d_in[1];
    float*  out = (float*)d_out;
    float4* ws  = (float4*)d_ws;   // 1024 * 16 B = 16 KB

    patch_stats_kernel<<<NPATCH, THREADS1, 0, stream>>>(labels, preds, ws);
    final_reduce_kernel<<<1, 256, 0, stream>>>(ws, out);
}

// Round 2
// 37.536 us; speedup vs baseline: 1.3859x; 1.3859x over previous
//
#include <hip/hip_runtime.h>
#include <math.h>

// Problem constants (B,C,H,W)=(16,1,1024,1024), patch=128
constexpr int B_ = 16;
constexpr int HW = 1024;
constexpr int P  = 128;
constexpr int NPATCH = 1024;       // 16 samples * 8 * 8
constexpr int THREADS1 = 512;

// Kernel 1: one block per 128x128 patch.
// Per-patch record: {bce_partial_sum, min(pred), max(pred), valid}
__global__ __launch_bounds__(THREADS1)
void patch_stats_kernel(const float* __restrict__ labels,
                        const float* __restrict__ preds,
                        float4* __restrict__ ws)
{
    const int pid = blockIdx.x;
    const int s  = pid >> 6;          // sample
    const int ph = (pid >> 3) & 7;    // patch row
    const int pw = pid & 7;           // patch col
    const size_t base = (size_t)s * (HW * HW) + (size_t)ph * P * HW + (size_t)pw * P;

    const int tid  = threadIdx.x;
    const int col4 = (tid & 31) << 2; // float offset within a 128-float row
    const int row0 = tid >> 5;        // 0..15; 512 threads cover 16 rows per pass

    // Split BCE accumulators: bce = sum_relu - sum_xt + ln2 * sum_log2(1+e)
    float sum_relu = 0.0f, sum_xt = 0.0f, sum_l2 = 0.0f;
    float xmin =  3.0e38f, xmax = -3.0e38f;
    float tmin =  3.0e38f, tmax = -3.0e38f;

    const float NLOG2E = -1.4426950408889634f; // -log2(e)

    const float4* px = reinterpret_cast<const float4*>(preds  + base + (size_t)row0 * HW + col4);
    const float4* pt = reinterpret_cast<const float4*>(labels + base + (size_t)row0 * HW + col4);
    constexpr int STRIDE4 = 16 * HW / 4; // float4 stride for 16 rows

    #pragma unroll
    for (int it = 0; it < 8; ++it) {
        const float4 x4 = px[(size_t)it * STRIDE4];
        const float4 t4 = pt[(size_t)it * STRIDE4];
        const float xs[4] = {x4.x, x4.y, x4.z, x4.w};
        const float ts[4] = {t4.x, t4.y, t4.z, t4.w};
        #pragma unroll
        for (int j = 0; j < 4; ++j) {
            const float x = xs[j], t = ts[j];
            // softplus tail: log2(1 + 2^(-|x|*log2e)), summed in log2 domain
            const float e = __builtin_amdgcn_exp2f(fabsf(x) * NLOG2E);
            sum_l2   += __builtin_amdgcn_logf(1.0f + e);   // v_log_f32 = log2
            sum_relu += fmaxf(x, 0.0f);
            sum_xt    = fmaf(x, t, sum_xt);
            xmin = fminf(xmin, x); xmax = fmaxf(xmax, x);
            tmin = fminf(tmin, t); tmax = fmaxf(tmax, t);
        }
    }

    const float LN2 = 0.6931471805599453f;
    float bce = sum_relu - sum_xt + LN2 * sum_l2;

    // wave(64) reduction
    #pragma unroll
    for (int o = 32; o > 0; o >>= 1) {
        bce += __shfl_down(bce, o);
        xmin = fminf(xmin, __shfl_down(xmin, o));
        xmax = fmaxf(xmax, __shfl_down(xmax, o));
        tmin = fminf(tmin, __shfl_down(tmin, o));
        tmax = fmaxf(tmax, __shfl_down(tmax, o));
    }

    __shared__ float s_bce[8], s_xmin[8], s_xmax[8], s_tmin[8], s_tmax[8];
    const int wave = tid >> 6;
    const int lane = tid & 63;
    if (lane == 0) {
        s_bce[wave] = bce;  s_xmin[wave] = xmin; s_xmax[wave] = xmax;
        s_tmin[wave] = tmin; s_tmax[wave] = tmax;
    }
    __syncthreads();
    if (tid == 0) {
        float b = 0.0f, xi = 3.0e38f, xa = -3.0e38f, ti = 3.0e38f, ta = -3.0e38f;
        #pragma unroll
        for (int w = 0; w < THREADS1 / 64; ++w) {
            b += s_bce[w];
            xi = fminf(xi, s_xmin[w]); xa = fmaxf(xa, s_xmax[w]);
            ti = fminf(ti, s_tmin[w]); ta = fmaxf(ta, s_tmax[w]);
        }
        // valid == (min t < 0.5) && (max t > 0.5)
        const float valid = (ti < 0.5f && ta > 0.5f) ? 1.0f : 0.0f;
        ws[pid] = make_float4(b, xi, xa, valid);
    }
}

// Kernel 2: reduce 1024 patch records to the scalar loss. Overwrites out[0].
__global__ __launch_bounds__(256)
void final_reduce_kernel(const float4* __restrict__ ws, float* __restrict__ out)
{
    const int tid = threadIdx.x;
    float bce = 0.0f, topo = 0.0f;
    for (int i = tid; i < NPATCH; i += 256) {
        const float4 rec = ws[i];
        bce += rec.x;
        if (rec.w > 0.5f) {
            // lh = sigmoid(1 - x) decreasing in x: pmax = sig(1-xmin), pmin = sig(1-xmax)
            const float pmax = 1.0f / (1.0f + __expf(rec.y - 1.0f));
            const float pmin = 1.0f / (1.0f + __expf(rec.z - 1.0f));
            topo += (pmax - 1.0f) * (pmax - 1.0f) + pmin * pmin;
        }
    }
    #pragma unroll
    for (int o = 32; o > 0; o >>= 1) {
        bce  += __shfl_down(bce, o);
        topo += __shfl_down(topo, o);
    }
    __shared__ float s_b[4], s_t[4];
    const int wave = tid >> 6;
    const int lane = tid & 63;
    if (lane == 0) { s_b[wave] = bce; s_t[wave] = topo; }
    __syncthreads();
    if (tid == 0) {
        const float bt = s_b[0] + s_b[1] + s_b[2] + s_b[3];
        const float tt = s_t[0] + s_t[1] + s_t[2] + s_t[3];
        out[0] = bt / (float)((size_t)B_ * HW * HW) + tt / (float)B_;
    }
}

extern "C" void kernel_launch(void* const* d_in, const int* in_sizes, int n_in,
                              void* d_out, int out_size, void* d_ws, size_t ws_size,
                              hipStream_t stream) {
    const float* labels = (const float*)d_in[0];
    const float* preds  = (const float*)d_in[1];
    float*  out = (float*)d_out;
    float4* ws  = (float4*)d_ws;   // 1024 * 16 B = 16 KB

    patch_stats_kernel<<<NPATCH, THREADS1, 0, stream>>>(labels, preds, ws);
    final_reduce_kernel<<<1, 256, 0, stream>>>(ws, out);
}

// Round 3
// 31.250 us; speedup vs baseline: 1.6647x; 1.2011x over previous
//
#include <hip/hip_runtime.h>
#include <math.h>

// Problem constants (B,C,H,W)=(16,1,1024,1024), patch=128
constexpr int B_ = 16;
constexpr int HW = 1024;
constexpr int P  = 128;
constexpr int NPATCH = 1024;       // 16 samples * 8 * 8
constexpr int THREADS1 = 512;

// Kernel 1: one block per 128x128 patch.
// Per-patch record: {bce_partial_sum, min(pred), max(pred), valid}
__global__ __launch_bounds__(THREADS1)
void patch_stats_kernel(const float* __restrict__ labels,
                        const float* __restrict__ preds,
                        float4* __restrict__ ws)
{
    const int pid = blockIdx.x;
    const int s  = pid >> 6;          // sample
    const int ph = (pid >> 3) & 7;    // patch row
    const int pw = pid & 7;           // patch col
    const size_t base = (size_t)s * (HW * HW) + (size_t)ph * P * HW + (size_t)pw * P;

    const int tid  = threadIdx.x;
    const int col4 = (tid & 31) << 2; // float offset within a 128-float row
    const int row0 = tid >> 5;        // 0..15; 512 threads cover 16 rows per pass

    const float4* px = reinterpret_cast<const float4*>(preds  + base + (size_t)row0 * HW + col4);
    const float4* pt = reinterpret_cast<const float4*>(labels + base + (size_t)row0 * HW + col4);
    constexpr int STRIDE4 = 16 * HW / 4; // float4 stride for 16 rows

    // ---- Deep prefetch: issue all 16 global_load_dwordx4 before consuming ----
    float4 xb[8], tb[8];
    #pragma unroll
    for (int it = 0; it < 8; ++it) xb[it] = px[(size_t)it * STRIDE4];
    #pragma unroll
    for (int it = 0; it < 8; ++it) tb[it] = pt[(size_t)it * STRIDE4];

    // Split BCE accumulators: bce = sum_relu - sum_xt + ln2 * sum_log2(1+e)
    float sum_relu = 0.0f, sum_xt = 0.0f, sum_l2 = 0.0f;
    float xmin =  3.0e38f, xmax = -3.0e38f;
    float tmin =  3.0e38f, tmax = -3.0e38f;

    const float NLOG2E = -1.4426950408889634f; // -log2(e)

    #pragma unroll
    for (int it = 0; it < 8; ++it) {
        const float xs[4] = {xb[it].x, xb[it].y, xb[it].z, xb[it].w};
        const float ts[4] = {tb[it].x, tb[it].y, tb[it].z, tb[it].w};
        #pragma unroll
        for (int j = 0; j < 4; ++j) {
            const float x = xs[j], t = ts[j];
            // softplus tail: log2(1 + 2^(-|x|*log2e)), summed in log2 domain
            const float e = __builtin_amdgcn_exp2f(fabsf(x) * NLOG2E);
            sum_l2   += __builtin_amdgcn_logf(1.0f + e);   // v_log_f32 = log2
            sum_relu += fmaxf(x, 0.0f);
            sum_xt    = fmaf(x, t, sum_xt);
            xmin = fminf(xmin, x); xmax = fmaxf(xmax, x);
            tmin = fminf(tmin, t); tmax = fmaxf(tmax, t);
        }
    }

    const float LN2 = 0.6931471805599453f;
    float bce = sum_relu - sum_xt + LN2 * sum_l2;

    // wave(64) reduction
    #pragma unroll
    for (int o = 32; o > 0; o >>= 1) {
        bce += __shfl_down(bce, o);
        xmin = fminf(xmin, __shfl_down(xmin, o));
        xmax = fmaxf(xmax, __shfl_down(xmax, o));
        tmin = fminf(tmin, __shfl_down(tmin, o));
        tmax = fmaxf(tmax, __shfl_down(tmax, o));
    }

    __shared__ float s_bce[8], s_xmin[8], s_xmax[8], s_tmin[8], s_tmax[8];
    const int wave = tid >> 6;
    const int lane = tid & 63;
    if (lane == 0) {
        s_bce[wave] = bce;  s_xmin[wave] = xmin; s_xmax[wave] = xmax;
        s_tmin[wave] = tmin; s_tmax[wave] = tmax;
    }
    __syncthreads();
    if (tid == 0) {
        float b = 0.0f, xi = 3.0e38f, xa = -3.0e38f, ti = 3.0e38f, ta = -3.0e38f;
        #pragma unroll
        for (int w = 0; w < THREADS1 / 64; ++w) {
            b += s_bce[w];
            xi = fminf(xi, s_xmin[w]); xa = fmaxf(xa, s_xmax[w]);
            ti = fminf(ti, s_tmin[w]); ta = fmaxf(ta, s_tmax[w]);
        }
        // valid == (min t < 0.5) && (max t > 0.5)
        const float valid = (ti < 0.5f && ta > 0.5f) ? 1.0f : 0.0f;
        ws[pid] = make_float4(b, xi, xa, valid);
    }
}

// Kernel 2: reduce 1024 patch records to the scalar loss. Overwrites out[0].
__global__ __launch_bounds__(256)
void final_reduce_kernel(const float4* __restrict__ ws, float* __restrict__ out)
{
    const int tid = threadIdx.x;
    float bce = 0.0f, topo = 0.0f;
    for (int i = tid; i < NPATCH; i += 256) {
        const float4 rec = ws[i];
        bce += rec.x;
        if (rec.w > 0.5f) {
            // lh = sigmoid(1 - x) decreasing in x: pmax = sig(1-xmin), pmin = sig(1-xmax)
            const float pmax = 1.0f / (1.0f + __expf(rec.y - 1.0f));
            const float pmin = 1.0f / (1.0f + __expf(rec.z - 1.0f));
            topo += (pmax - 1.0f) * (pmax - 1.0f) + pmin * pmin;
        }
    }
    #pragma unroll
    for (int o = 32; o > 0; o >>= 1) {
        bce  += __shfl_down(bce, o);
        topo += __shfl_down(topo, o);
    }
    __shared__ float s_b[4], s_t[4];
    const int wave = tid >> 6;
    const int lane = tid & 63;
    if (lane == 0) { s_b[wave] = bce; s_t[wave] = topo; }
    __syncthreads();
    if (tid == 0) {
        const float bt = s_b[0] + s_b[1] + s_b[2] + s_b[3];
        const float tt = s_t[0] + s_t[1] + s_t[2] + s_t[3];
        out[0] = bt / (float)((size_t)B_ * HW * HW) + tt / (float)B_;
    }
}

extern "C" void kernel_launch(void* const* d_in, const int* in_sizes, int n_in,
                              void* d_out, int out_size, void* d_ws, size_t ws_size,
                              hipStream_t stream) {
    const float* labels = (const float*)d_in[0];
    const float* preds  = (const float*)d_in[1];
    float*  out = (float*)d_out;
    float4* ws  = (float4*)d_ws;   // 1024 * 16 B = 16 KB

    patch_stats_kernel<<<NPATCH, THREADS1, 0, stream>>>(labels, preds, ws);
    final_reduce_kernel<<<1, 256, 0, stream>>>(ws, out);
}